// Round 1
// baseline (275.167 us; speedup 1.0000x reference)
//
#include <hip/hip_runtime.h>
#include <hip/hip_bf16.h>

#define NB 100
#define NT 500
#define CIN 300
#define COUT 500
#define M_TOT (NB * NT)   // 50000

constexpr int BM = 128, BN = 128, BK = 32;

// C[m][o] = sum_k X[m][k] * W[o][k]   (X: [M,300], W: [500,300], C: [M,500])
__global__ __launch_bounds__(256) void gemm_f32(
    const float* __restrict__ X, const float* __restrict__ W, float* __restrict__ C)
{
    __shared__ float As[BK][BM + 4];
    __shared__ float Bs[BK][BN + 4];

    const int ntiles_n = (COUT + BN - 1) / BN;  // 4
    const int mtile = blockIdx.x / ntiles_n;
    const int ntile = blockIdx.x % ntiles_n;
    const int m0 = mtile * BM, n0 = ntile * BN;

    const int tid = threadIdx.x;
    const int tx = tid & 15, ty = tid >> 4;
    const int lr = tid >> 3;          // 0..31 : row within 32-row staging group
    const int lk = (tid & 7) << 2;    // 0,4,...,28 : k offset (float4)

    float acc[8][8];
    #pragma unroll
    for (int i = 0; i < 8; ++i)
        #pragma unroll
        for (int j = 0; j < 8; ++j) acc[i][j] = 0.f;

    for (int k0 = 0; k0 < CIN; k0 += BK) {
        const int kk = k0 + lk;
        const bool kv = (kk < CIN);   // CIN divisible by 4, so float4-granular
        #pragma unroll
        for (int p = 0; p < 4; ++p) {
            int row = p * 32 + lr;
            int m = m0 + row;
            float4 v = make_float4(0.f, 0.f, 0.f, 0.f);
            if (kv && m < M_TOT) v = *(const float4*)(X + (size_t)m * CIN + kk);
            As[lk + 0][row] = v.x; As[lk + 1][row] = v.y;
            As[lk + 2][row] = v.z; As[lk + 3][row] = v.w;
        }
        #pragma unroll
        for (int p = 0; p < 4; ++p) {
            int row = p * 32 + lr;
            int o = n0 + row;
            float4 v = make_float4(0.f, 0.f, 0.f, 0.f);
            if (kv && o < COUT) v = *(const float4*)(W + (size_t)o * CIN + kk);
            Bs[lk + 0][row] = v.x; Bs[lk + 1][row] = v.y;
            Bs[lk + 2][row] = v.z; Bs[lk + 3][row] = v.w;
        }
        __syncthreads();
        #pragma unroll 8
        for (int k = 0; k < BK; ++k) {
            float4 a0 = *(const float4*)&As[k][ty * 8];
            float4 a1 = *(const float4*)&As[k][ty * 8 + 4];
            float4 b0 = *(const float4*)&Bs[k][tx * 8];
            float4 b1 = *(const float4*)&Bs[k][tx * 8 + 4];
            float a[8] = {a0.x, a0.y, a0.z, a0.w, a1.x, a1.y, a1.z, a1.w};
            float b[8] = {b0.x, b0.y, b0.z, b0.w, b1.x, b1.y, b1.z, b1.w};
            #pragma unroll
            for (int i = 0; i < 8; ++i)
                #pragma unroll
                for (int j = 0; j < 8; ++j)
                    acc[i][j] += a[i] * b[j];
        }
        __syncthreads();
    }

    #pragma unroll
    for (int i = 0; i < 8; ++i) {
        int m = m0 + ty * 8 + i;
        if (m >= M_TOT) continue;
        int o = n0 + tx * 8;
        float* cp = C + (size_t)m * COUT + o;
        if (o < COUT)
            *(float4*)cp = make_float4(acc[i][0], acc[i][1], acc[i][2], acc[i][3]);
        if (o + 4 < COUT)
            *(float4*)(cp + 4) = make_float4(acc[i][4], acc[i][5], acc[i][6], acc[i][7]);
    }
}

// In-place LIF scan over t for each neuron n = b*COUT + o.
// C holds x_lin on entry, spikes on exit. threshold == 1.
__global__ __launch_bounds__(256) void lif_scan(
    const float* __restrict__ alpha, float* __restrict__ C)
{
    const int n = blockIdx.x * blockDim.x + threadIdx.x;
    if (n >= NB * COUT) return;
    const int b = n / COUT, o = n % COUT;
    const float a = alpha[n];
    float v = 0.f;
    float* p = C + (size_t)b * NT * COUT + o;

    constexpr int U = 10;   // 500 = 50 * 10
    for (int t0 = 0; t0 < NT; t0 += U) {
        float xl[U];
        #pragma unroll
        for (int u = 0; u < U; ++u) xl[u] = p[(size_t)(t0 + u) * COUT];
        float s[U];
        #pragma unroll
        for (int u = 0; u < U; ++u) {
            float vp = a * v + xl[u];
            vp = fmaxf(vp, -1.f);
            float sp = (vp >= 1.f) ? floorf(vp) : 0.f;
            v = vp - sp;
            s[u] = sp;
        }
        #pragma unroll
        for (int u = 0; u < U; ++u) p[(size_t)(t0 + u) * COUT] = s[u];
    }
}

extern "C" void kernel_launch(void* const* d_in, const int* in_sizes, int n_in,
                              void* d_out, int out_size, void* d_ws, size_t ws_size,
                              hipStream_t stream) {
    const float* X     = (const float*)d_in[0];   // [100,500,300]
    const float* W     = (const float*)d_in[1];   // [500,300]
    const float* alpha = (const float*)d_in[2];   // [50000]
    float* C = (float*)d_out;                     // [100,500,500]

    const int mtiles = (M_TOT + BM - 1) / BM;     // 391
    const int ntiles = (COUT + BN - 1) / BN;      // 4
    gemm_f32<<<dim3(mtiles * ntiles), dim3(256), 0, stream>>>(X, W, C);

    const int nneur = NB * COUT;                  // 50000
    lif_scan<<<dim3((nneur + 255) / 256), dim3(256), 0, stream>>>(alpha, C);
}